// Round 13
// baseline (272.218 us; speedup 1.0000x reference)
//
#include <hip/hip_runtime.h>

typedef float f32x4 __attribute__((ext_vector_type(4)));
typedef short s16x8 __attribute__((ext_vector_type(8)));
typedef unsigned int u32;
typedef u32 u32x4 __attribute__((ext_vector_type(4)));
typedef unsigned long long u64;
typedef unsigned short ush;

#define CD    256
#define NB    64
#define NBETA 512
#define NHID  512
#define PPB   32    // positions per fused block (16 pairs)

__device__ __forceinline__ ush f2bf(float x) {
    u32 u = __builtin_bit_cast(u32, x);
    u += 0x7fffu + ((u >> 16) & 1u);
    return (ush)(u >> 16);
}
__device__ __forceinline__ float bf2f(ush h) {
    u32 u = ((u32)h) << 16;
    return __builtin_bit_cast(float, u);
}
__device__ __forceinline__ u32 cvtpk(float lo, float hi) {
    u32 r;
    asm("v_cvt_pk_bf16_f32 %0, %1, %2" : "=v"(r) : "v"(lo), "v"(hi));
    return r;
}
__device__ __forceinline__ float fexp2(float x) {  // 2^x
    float r;
    asm("v_exp_f32 %0, %1" : "=v"(r) : "v"(x));
    return r;
}

// ---------------------------------------------------------------------------
// Prep (unchanged, proven): hws[b][beta] bf16; wwb = bf16(W_w).
// ---------------------------------------------------------------------------
__global__ __launch_bounds__(512) void prep_kernel(
    const float* __restrict__ h_t, const float* __restrict__ W_h_w,
    const float* __restrict__ W_h_b, const float* __restrict__ W_w,
    const float* __restrict__ W_b,
    ush* __restrict__ hws, ush* __restrict__ wwb)
{
    const int blk = blockIdx.x;
    const int tid = threadIdx.x;
    if (blk < NB) {
        __shared__ float hrow[NHID];
        hrow[tid] = h_t[blk * NHID + tid];
        __syncthreads();
        const float* wr = W_h_w + tid * NHID;
        float a0 = 0.f, a1 = 0.f, a2 = 0.f, a3 = 0.f;
        #pragma unroll 4
        for (int h = 0; h < NHID; h += 4) {
            f32x4 wv = *(const f32x4*)(wr + h);
            a0 = fmaf(wv.x, hrow[h], a0);
            a1 = fmaf(wv.y, hrow[h + 1], a1);
            a2 = fmaf(wv.z, hrow[h + 2], a2);
            a3 = fmaf(wv.w, hrow[h + 3], a3);
        }
        float acc = (a0 + a1) + (a2 + a3) + W_h_b[tid] + W_b[tid];
        hws[blk * NBETA + tid] = f2bf(acc);   // [b][beta]
    } else {
        const int idx = ((blk - NB) * 512 + tid) * 8;
        f32x4 a = *(const f32x4*)(W_w + idx);
        f32x4 b = *(const f32x4*)(W_w + idx + 4);
        s16x8 pk;
        pk[0] = (short)f2bf(a.x); pk[1] = (short)f2bf(a.y);
        pk[2] = (short)f2bf(a.z); pk[3] = (short)f2bf(a.w);
        pk[4] = (short)f2bf(b.x); pk[5] = (short)f2bf(b.y);
        pk[6] = (short)f2bf(b.z); pk[7] = (short)f2bf(b.w);
        *(s16x8*)(wwb + idx) = pk;
    }
}

// ---------------------------------------------------------------------------
// Fused: 1024 thr = 16 waves x 32 betas, block = (b-half, 32 positions).
// Round-13: ONE barrier per POSITION PAIR (halves the sync convoy).
//   - 6-buffer Vt rotation (96 KB): slot distances >=3 between any writer
//     and any post-barrier reader -> race-free with 1 barrier/pair.
//   - interleaved staging: stage(2t+2); issue(2t+3); K(2t); stage(2t+3);
//     issue(2t+4); K(2t+1) -> nv stays 8 regs (reg peak ~116 < 128).
//   - ew in [wave][b] layout: e-sum = 16 conflict-free broadcast b32 reads
//     (old [b][wave] pad-20 b128 read was 4-way bank-conflicted).
// ---------------------------------------------------------------------------
__global__ __launch_bounds__(1024) void fused(
    const float* __restrict__ V,
    const ush* __restrict__ wwb,
    const ush* __restrict__ hws,
    const float* __restrict__ beta_w,
    const float* __restrict__ beta_b,
    float* __restrict__ num,
    float* __restrict__ lsum)
{
    __shared__ __align__(16) char VtB[6 * 16384];  // 6 x [32 b][256 c] bf16 swz
    __shared__ float nbS[NBETA];                   // -2*beta_w
    __shared__ float ewS[2][16][64];               // [parity][wave][q*32+b]

    const int tid = threadIdx.x;
    const int l = tid & 63, w = tid >> 6, g = l >> 4, r = l & 15;
    const int bl = tid & 31, cs = tid >> 5;        // b-lane, c-slice of 8
    const int bh = blockIdx.x & 1, chunk = blockIdx.x >> 1;

    if (tid < NBETA) nbS[tid] = -2.f * beta_w[tid];
    const float bbias = beta_b[0];

    // base = sum of this lane's 8 bw values (position-invariant)
    float base;
    {
        f32x4 t0 = *(const f32x4*)(beta_w + w * 32 + g * 4);
        f32x4 t1 = *(const f32x4*)(beta_w + w * 32 + 16 + g * 4);
        base = (t0.x + t0.y) + (t0.z + t0.w) + (t1.x + t1.y) + (t1.z + t1.w);
    }

    // permanent A fragments: beta = w*32 + m*16 + r  (64 VGPR)
    const ush* wbase = wwb + (size_t)(w * 32 + r) * CD + g * 8;
    s16x8 a[2][8];
    #pragma unroll
    for (int m = 0; m < 2; ++m)
        #pragma unroll
        for (int ks = 0; ks < 8; ++ks)
            a[m][ks] = *(const s16x8*)(wbase + m * (16 * CD) + ks * 32);

    // permanent hterm: ua[m][n] = betas (w*32+m*16+g*4..+3) at b=bh*32+n*16+r
    const ush* hbase = hws + (size_t)(bh * 32 + r) * NBETA + w * 32 + g * 4;
    u64 ua[2][2];
    #pragma unroll
    for (int m = 0; m < 2; ++m)
        #pragma unroll
        for (int n = 0; n < 2; ++n)
            ua[m][n] = *(const u64*)(hbase + n * (16 * NBETA) + m * 16);

    const int p0 = chunk * PPB;
    const float* vbase = V + (size_t)p0 * (CD * NB) + bh * 32 + bl;
    const int wswz = (bl & 15) << 4;
    const int rswz = r << 4;
    const int sloc = bl * 512 + ((cs * 16) ^ wswz);   // stage/wsum address

    float cacc[8];
    #pragma unroll
    for (int j = 0; j < 8; ++j) cacc[j] = 0.f;
    float lacc = 0.f;

    float nv[8];

#define LOADP(P)                                                              \
    {                                                                         \
        const float* vp = vbase + (size_t)(P) * (CD * NB);                    \
        _Pragma("unroll")                                                     \
        for (int j = 0; j < 8; ++j)                                           \
            nv[j] = __builtin_nontemporal_load(vp + (cs * 8 + j) * NB);       \
    }
#define STAGE(OFF)                                                            \
    {                                                                         \
        u32x4 pk = {cvtpk(nv[0], nv[1]), cvtpk(nv[2], nv[3]),                 \
                    cvtpk(nv[4], nv[5]), cvtpk(nv[6], nv[7])};                \
        *(u32x4*)(VtB + (OFF) + sloc) = pk;                                   \
    }
#define KEPI(OFF, NSEL, PE)                                                   \
    {                                                                         \
        const char* vrow = VtB + (OFF) + r * 512;                             \
        f32x4 acc[2];                                                         \
        _Pragma("unroll")                                                     \
        for (int m = 0; m < 2; ++m) {                                         \
            u64 h = ua[m][NSEL];                                              \
            acc[m] = (f32x4){bf2f((ush)h), bf2f((ush)(h >> 16)),              \
                             bf2f((ush)(h >> 32)), bf2f((ush)(h >> 48))};     \
        }                                                                     \
        _Pragma("unroll")                                                     \
        for (int ks = 0; ks < 8; ++ks) {                                      \
            const int off = (((ks << 6) | (g << 4)) ^ rswz) + (NSEL) * 8192;  \
            s16x8 bf = *(const s16x8*)(vrow + off);                           \
            _Pragma("unroll")                                                 \
            for (int m = 0; m < 2; ++m)                                       \
                acc[m] = __builtin_amdgcn_mfma_f32_16x16x32_bf16(             \
                    a[m][ks], bf, acc[m], 0, 0, 0);                           \
        }                                                                     \
        PE = base;                                                            \
        _Pragma("unroll")                                                     \
        for (int m = 0; m < 2; ++m) {                                         \
            f32x4 nbv = *(const f32x4*)(&nbS[w * 32 + m * 16 + g * 4]);       \
            _Pragma("unroll")                                                 \
            for (int q = 0; q < 4; ++q) {                                     \
                float s = __builtin_amdgcn_rcpf(                              \
                    1.f + fexp2(acc[m][q] * 2.8853900817779268f));            \
                PE = fmaf(nbv[q], s, PE);                                     \
            }                                                                 \
        }                                                                     \
    }

    // prologue: stage pos0 -> slot0, pos1 -> slot1; issue pos2 loads
    LOADP(0) STAGE(0)
    LOADP(1) STAGE(16384)
    LOADP(2)
    __syncthreads();

    int offR = 0;   // slot base of pos 2t; cycles 0,32768,65536
    for (int t = 0; t < PPB / 2; ++t) {
        int offW = offR + 32768; if (offW >= 98304) offW -= 98304;
        const int par = t & 1;

        // stage(2t+2) from nv; issue loads(2t+3)
        if (t < 15) { STAGE(offW) LOADP(2 * t + 3) }

        // K + epilogue for pos 2t (n=0 half then n=1 half of b)
        float peA0, peA1;
        KEPI(offR, 0, peA0)
        KEPI(offR, 1, peA1)

        // stage(2t+3); issue loads(2t+4)
        if (t < 15) { STAGE(offW + 16384) }
        if (t < 14) { LOADP(2 * t + 4) }

        // K + epilogue for pos 2t+1
        float peB0, peB1;
        KEPI(offR + 16384, 0, peB0)
        KEPI(offR + 16384, 1, peB1)

        // cross-lane reduce (over g) + ew writes [wave][q*32+b]
        peA0 += __shfl_xor(peA0, 16, 64); peA0 += __shfl_xor(peA0, 32, 64);
        peA1 += __shfl_xor(peA1, 16, 64); peA1 += __shfl_xor(peA1, 32, 64);
        peB0 += __shfl_xor(peB0, 16, 64); peB0 += __shfl_xor(peB0, 32, 64);
        peB1 += __shfl_xor(peB1, 16, 64); peB1 += __shfl_xor(peB1, 32, 64);
        if (l < 16) {
            ewS[par][w][l]      = peA0;
            ewS[par][w][16 + l] = peA1;
            ewS[par][w][32 + l] = peB0;
            ewS[par][w][48 + l] = peB1;
        }

        __syncthreads();   // the ONLY barrier per pair

        // e-sum (conflict-free broadcast b32) + wsum for both positions
        {
            float e0 = bbias, e1 = bbias;
            #pragma unroll
            for (int wv = 0; wv < 16; ++wv) {
                e0 += ewS[par][wv][bl];
                e1 += ewS[par][wv][32 + bl];
            }
            float wgtA = __expf(e0), wgtB = __expf(e1);
            lacc += wgtA + wgtB;
            s16x8 vA = *(const s16x8*)(VtB + offR + sloc);
            s16x8 vB = *(const s16x8*)(VtB + offR + 16384 + sloc);
            #pragma unroll
            for (int j = 0; j < 8; ++j) {
                cacc[j] = fmaf(wgtA, bf2f((ush)vA[j]), cacc[j]);
                cacc[j] = fmaf(wgtB, bf2f((ush)vB[j]), cacc[j]);
            }
        }

        offR = offW;
    }

#undef KEPI
#undef STAGE
#undef LOADP

    // partials: num[block][32 b][256 c]
    float* np = num + (size_t)blockIdx.x * (32 * CD) + bl * CD + cs * 8;
    *(f32x4*)(np)     = (f32x4){cacc[0], cacc[1], cacc[2], cacc[3]};
    *(f32x4*)(np + 4) = (f32x4){cacc[4], cacc[5], cacc[6], cacc[7]};
    if (cs == 0) lsum[blockIdx.x * 32 + bl] = lacc;
}

// ---------------------------------------------------------------------------
// Combine (unchanged): 256 blocks = (b 64 x cq 4); 256 thr = (cl 64 x kq 4).
// ---------------------------------------------------------------------------
__global__ __launch_bounds__(256) void combine4(
    const float* __restrict__ num, const float* __restrict__ lsum,
    float* __restrict__ out)
{
    __shared__ float rs[4][64];
    __shared__ float rl[4][64];
    const int b = blockIdx.x >> 2, cq = blockIdx.x & 3;
    const int bh = b >> 5, blr = b & 31;
    const int cl = threadIdx.x & 63, kq = threadIdx.x >> 6;

    float s = 0.f, ls = 0.f;
    #pragma unroll 4
    for (int ch = kq * 32; ch < kq * 32 + 32; ++ch) {
        const int blk = ch * 2 + bh;
        s += num[(size_t)blk * (32 * CD) + blr * CD + cq * 64 + cl];
        ls += lsum[blk * 32 + blr];
    }
    rs[kq][cl] = s; rl[kq][cl] = ls;
    __syncthreads();
    if (kq == 0) {
        float sn = rs[0][cl] + rs[1][cl] + rs[2][cl] + rs[3][cl];
        float sl = rl[0][cl] + rl[1][cl] + rl[2][cl] + rl[3][cl];
        out[b * CD + cq * 64 + cl] = sn / sl;
    }
}

extern "C" void kernel_launch(void* const* d_in, const int* in_sizes, int n_in,
                              void* d_out, int out_size, void* d_ws, size_t ws_size,
                              hipStream_t stream)
{
    (void)in_sizes; (void)n_in; (void)out_size; (void)ws_size;
    const float* V      = (const float*)d_in[0];
    const float* h_t    = (const float*)d_in[1];
    const float* W_h_w  = (const float*)d_in[2];
    const float* W_h_b  = (const float*)d_in[3];
    const float* W_w    = (const float*)d_in[4];
    const float* W_b    = (const float*)d_in[5];
    const float* beta_w = (const float*)d_in[6];
    const float* beta_b = (const float*)d_in[7];

    char* ws = (char*)d_ws;
    ush*   wwb = (ush*)ws;                                   // 256 KB
    ush*   hws = (ush*)(ws + 262144);                        // 64 KB
    float* num = (float*)(ws + 262144 + 65536);              // 8.4 MB
    float* lsm = (float*)(ws + 262144 + 65536 + 8388608);    // 32 KB

    hipLaunchKernelGGL(prep_kernel, dim3(96), dim3(512), 0, stream,
                       h_t, W_h_w, W_h_b, W_w, W_b, hws, wwb);
    hipLaunchKernelGGL(fused, dim3(256), dim3(1024), 0, stream,
                       V, wwb, hws, beta_w, beta_b, num, lsm);
    hipLaunchKernelGGL(combine4, dim3(256), dim3(256), 0, stream,
                       num, lsm, (float*)d_out);
}

// Round 14
// 161.677 us; speedup vs baseline: 1.6837x; 1.6837x over previous
//
#include <hip/hip_runtime.h>

typedef float f32x4 __attribute__((ext_vector_type(4)));
typedef short s16x8 __attribute__((ext_vector_type(8)));
typedef unsigned int u32;
typedef u32 u32x4 __attribute__((ext_vector_type(4)));
typedef unsigned long long u64;
typedef unsigned short ush;

#define CD    256
#define NB    64
#define NBETA 512
#define NHID  512
#define PPB   32    // positions per fused block (16 pairs)

__device__ __forceinline__ ush f2bf(float x) {
    u32 u = __builtin_bit_cast(u32, x);
    u += 0x7fffu + ((u >> 16) & 1u);
    return (ush)(u >> 16);
}
__device__ __forceinline__ float bf2f(ush h) {
    u32 u = ((u32)h) << 16;
    return __builtin_bit_cast(float, u);
}
__device__ __forceinline__ u32 cvtpk(float lo, float hi) {
    u32 r;
    asm("v_cvt_pk_bf16_f32 %0, %1, %2" : "=v"(r) : "v"(lo), "v"(hi));
    return r;
}
__device__ __forceinline__ float fexp2(float x) {  // 2^x
    float r;
    asm("v_exp_f32 %0, %1" : "=v"(r) : "v"(x));
    return r;
}

// ---------------------------------------------------------------------------
// Prep (unchanged, proven): hws[b][beta] bf16; wwb = bf16(W_w).
// ---------------------------------------------------------------------------
__global__ __launch_bounds__(512) void prep_kernel(
    const float* __restrict__ h_t, const float* __restrict__ W_h_w,
    const float* __restrict__ W_h_b, const float* __restrict__ W_w,
    const float* __restrict__ W_b,
    ush* __restrict__ hws, ush* __restrict__ wwb)
{
    const int blk = blockIdx.x;
    const int tid = threadIdx.x;
    if (blk < NB) {
        __shared__ float hrow[NHID];
        hrow[tid] = h_t[blk * NHID + tid];
        __syncthreads();
        const float* wr = W_h_w + tid * NHID;
        float a0 = 0.f, a1 = 0.f, a2 = 0.f, a3 = 0.f;
        #pragma unroll 4
        for (int h = 0; h < NHID; h += 4) {
            f32x4 wv = *(const f32x4*)(wr + h);
            a0 = fmaf(wv.x, hrow[h], a0);
            a1 = fmaf(wv.y, hrow[h + 1], a1);
            a2 = fmaf(wv.z, hrow[h + 2], a2);
            a3 = fmaf(wv.w, hrow[h + 3], a3);
        }
        float acc = (a0 + a1) + (a2 + a3) + W_h_b[tid] + W_b[tid];
        hws[blk * NBETA + tid] = f2bf(acc);   // [b][beta]
    } else {
        const int idx = ((blk - NB) * 512 + tid) * 8;
        f32x4 a = *(const f32x4*)(W_w + idx);
        f32x4 b = *(const f32x4*)(W_w + idx + 4);
        s16x8 pk;
        pk[0] = (short)f2bf(a.x); pk[1] = (short)f2bf(a.y);
        pk[2] = (short)f2bf(a.z); pk[3] = (short)f2bf(a.w);
        pk[4] = (short)f2bf(b.x); pk[5] = (short)f2bf(b.y);
        pk[6] = (short)f2bf(b.z); pk[7] = (short)f2bf(b.w);
        *(s16x8*)(wwb + idx) = pk;
    }
}

// ---------------------------------------------------------------------------
// Fused: 1024 thr = 16 waves x 32 betas, block = (b-half, 32 positions).
// Round-14 = round-13's pair schedule (ONE barrier per pair, 6-slot Vt)
// MINUS ~10 regs so it fits the HARD 128-reg cap of 1024-thr blocks
// (round-13 lesson: 1024 thr => 4 waves/SIMD min => 128 regs is a wall):
//   - hterm evicted to LDS htL (32 KB, XOR-swizzled) -> acc-init via
//     2x ds_read_b64 per K-chain (was ua[2][2] = 8 regs)
//   - pe written to ewS immediately after each reduction (no held pes)
// ---------------------------------------------------------------------------
__global__ __launch_bounds__(1024) void fused(
    const float* __restrict__ V,
    const ush* __restrict__ wwb,
    const ush* __restrict__ hws,
    const float* __restrict__ beta_w,
    const float* __restrict__ beta_b,
    float* __restrict__ num,
    float* __restrict__ lsum)
{
    __shared__ __align__(16) char VtB[6 * 16384];  // 6 x [32 b][256 c] bf16 swz
    __shared__ __align__(16) char htL[32 * 1024];  // [32 b][512 beta] bf16 swz
    __shared__ float nbS[NBETA];                   // -2*beta_w
    __shared__ float ewS[2][16][64];               // [parity][wave][q*32+b]

    const int tid = threadIdx.x;
    const int l = tid & 63, w = tid >> 6, g = l >> 4, r = l & 15;
    const int bl = tid & 31, cs = tid >> 5;        // b-lane, c-slice of 8
    const int bh = blockIdx.x & 1, chunk = blockIdx.x >> 1;

    if (tid < NBETA) nbS[tid] = -2.f * beta_w[tid];
    const float bbias = beta_b[0];

    // hterm -> LDS: thread (bl, cs) copies 16 ushorts of row bl,
    // 8-byte granule XOR swizzle by (row&15)<<3 (bijective per row).
    {
        const ush* src = hws + (size_t)(bh * 32 + bl) * NBETA + cs * 16;
        char* dst = htL + bl * 1024;
        const int swz = (bl & 15) << 3;
        #pragma unroll
        for (int k = 0; k < 4; ++k)
            *(u64*)(dst + ((cs * 32 + k * 8) ^ swz)) = *(const u64*)(src + k * 4);
    }

    // base = sum of this lane's 8 bw values (position-invariant)
    float base;
    {
        f32x4 t0 = *(const f32x4*)(beta_w + w * 32 + g * 4);
        f32x4 t1 = *(const f32x4*)(beta_w + w * 32 + 16 + g * 4);
        base = (t0.x + t0.y) + (t0.z + t0.w) + (t1.x + t1.y) + (t1.z + t1.w);
    }

    // permanent A fragments: beta = w*32 + m*16 + r  (64 VGPR)
    const ush* wbase = wwb + (size_t)(w * 32 + r) * CD + g * 8;
    s16x8 a[2][8];
    #pragma unroll
    for (int m = 0; m < 2; ++m)
        #pragma unroll
        for (int ks = 0; ks < 8; ++ks)
            a[m][ks] = *(const s16x8*)(wbase + m * (16 * CD) + ks * 32);

    const int p0 = chunk * PPB;
    const float* vbase = V + (size_t)p0 * (CD * NB) + bh * 32 + bl;
    const int wswz = (bl & 15) << 4;
    const int rswz = r << 4;
    const int sloc = bl * 512 + ((cs * 16) ^ wswz);   // stage/wsum address

    float cacc[8];
    #pragma unroll
    for (int j = 0; j < 8; ++j) cacc[j] = 0.f;
    float lacc = 0.f;

    float nv[8];

#define LOADP(P)                                                              \
    {                                                                         \
        const float* vp = vbase + (size_t)(P) * (CD * NB);                    \
        _Pragma("unroll")                                                     \
        for (int j = 0; j < 8; ++j)                                           \
            nv[j] = __builtin_nontemporal_load(vp + (cs * 8 + j) * NB);       \
    }
#define STAGE(OFF)                                                            \
    {                                                                         \
        u32x4 pk = {cvtpk(nv[0], nv[1]), cvtpk(nv[2], nv[3]),                 \
                    cvtpk(nv[4], nv[5]), cvtpk(nv[6], nv[7])};                \
        *(u32x4*)(VtB + (OFF) + sloc) = pk;                                   \
    }
// K-chain + epilogue for one (slot, b-half); writes its pe to ewS at EWOFF.
#define KEPI(OFF, NSEL, PAR, EWOFF)                                           \
    {                                                                         \
        const char* vrow = VtB + (OFF) + r * 512;                             \
        const char* hrow = htL + ((NSEL) * 16 + r) * 1024;                    \
        f32x4 acc[2];                                                         \
        _Pragma("unroll")                                                     \
        for (int m = 0; m < 2; ++m) {                                         \
            u64 h = *(const u64*)(hrow +                                      \
                ((w * 64 + m * 32 + g * 8) ^ (r << 3)));                      \
            acc[m] = (f32x4){bf2f((ush)h), bf2f((ush)(h >> 16)),              \
                             bf2f((ush)(h >> 32)), bf2f((ush)(h >> 48))};     \
        }                                                                     \
        _Pragma("unroll")                                                     \
        for (int ks = 0; ks < 8; ++ks) {                                      \
            const int off = (((ks << 6) | (g << 4)) ^ rswz) + (NSEL) * 8192;  \
            s16x8 bf = *(const s16x8*)(vrow + off);                           \
            _Pragma("unroll")                                                 \
            for (int m = 0; m < 2; ++m)                                       \
                acc[m] = __builtin_amdgcn_mfma_f32_16x16x32_bf16(             \
                    a[m][ks], bf, acc[m], 0, 0, 0);                           \
        }                                                                     \
        float pe = base;                                                      \
        _Pragma("unroll")                                                     \
        for (int m = 0; m < 2; ++m) {                                         \
            f32x4 nbv = *(const f32x4*)(&nbS[w * 32 + m * 16 + g * 4]);       \
            _Pragma("unroll")                                                 \
            for (int q = 0; q < 4; ++q) {                                     \
                float s = __builtin_amdgcn_rcpf(                              \
                    1.f + fexp2(acc[m][q] * 2.8853900817779268f));            \
                pe = fmaf(nbv[q], s, pe);                                     \
            }                                                                 \
        }                                                                     \
        pe += __shfl_xor(pe, 16, 64);                                         \
        pe += __shfl_xor(pe, 32, 64);                                         \
        if (l < 16) ewS[PAR][w][(EWOFF) + l] = pe;                            \
    }

    // prologue: stage pos0 -> slot0, pos1 -> slot1; issue pos2 loads
    LOADP(0) STAGE(0)
    LOADP(1) STAGE(16384)
    LOADP(2)
    __syncthreads();

    int offR = 0;   // slot base of pos 2t; cycles 0,32768,65536
    for (int t = 0; t < PPB / 2; ++t) {
        int offW = offR + 32768; if (offW >= 98304) offW -= 98304;
        const int par = t & 1;

        // stage(2t+2) from nv; issue loads(2t+3)
        if (t < 15) { STAGE(offW) LOADP(2 * t + 3) }

        // K + epilogue for pos 2t (both b-halves), pe -> ewS immediately
        KEPI(offR, 0, par, 0)
        KEPI(offR, 1, par, 16)

        // stage(2t+3); issue loads(2t+4)
        if (t < 15) { STAGE(offW + 16384) }
        if (t < 14) { LOADP(2 * t + 4) }

        // K + epilogue for pos 2t+1
        KEPI(offR + 16384, 0, par, 32)
        KEPI(offR + 16384, 1, par, 48)

        __syncthreads();   // the ONLY barrier per pair

        // e-sum (conflict-free broadcast b32) + wsum for both positions
        {
            float e0 = bbias, e1 = bbias;
            #pragma unroll
            for (int wv = 0; wv < 16; ++wv) {
                e0 += ewS[par][wv][bl];
                e1 += ewS[par][wv][32 + bl];
            }
            float wgtA = __expf(e0), wgtB = __expf(e1);
            lacc += wgtA + wgtB;
            s16x8 vA = *(const s16x8*)(VtB + offR + sloc);
            s16x8 vB = *(const s16x8*)(VtB + offR + 16384 + sloc);
            #pragma unroll
            for (int j = 0; j < 8; ++j) {
                cacc[j] = fmaf(wgtA, bf2f((ush)vA[j]), cacc[j]);
                cacc[j] = fmaf(wgtB, bf2f((ush)vB[j]), cacc[j]);
            }
        }

        offR = offW;
    }

#undef KEPI
#undef STAGE
#undef LOADP

    // partials: num[block][32 b][256 c]
    float* np = num + (size_t)blockIdx.x * (32 * CD) + bl * CD + cs * 8;
    *(f32x4*)(np)     = (f32x4){cacc[0], cacc[1], cacc[2], cacc[3]};
    *(f32x4*)(np + 4) = (f32x4){cacc[4], cacc[5], cacc[6], cacc[7]};
    if (cs == 0) lsum[blockIdx.x * 32 + bl] = lacc;
}

// ---------------------------------------------------------------------------
// Combine (unchanged): 256 blocks = (b 64 x cq 4); 256 thr = (cl 64 x kq 4).
// ---------------------------------------------------------------------------
__global__ __launch_bounds__(256) void combine4(
    const float* __restrict__ num, const float* __restrict__ lsum,
    float* __restrict__ out)
{
    __shared__ float rs[4][64];
    __shared__ float rl[4][64];
    const int b = blockIdx.x >> 2, cq = blockIdx.x & 3;
    const int bh = b >> 5, blr = b & 31;
    const int cl = threadIdx.x & 63, kq = threadIdx.x >> 6;

    float s = 0.f, ls = 0.f;
    #pragma unroll 4
    for (int ch = kq * 32; ch < kq * 32 + 32; ++ch) {
        const int blk = ch * 2 + bh;
        s += num[(size_t)blk * (32 * CD) + blr * CD + cq * 64 + cl];
        ls += lsum[blk * 32 + blr];
    }
    rs[kq][cl] = s; rl[kq][cl] = ls;
    __syncthreads();
    if (kq == 0) {
        float sn = rs[0][cl] + rs[1][cl] + rs[2][cl] + rs[3][cl];
        float sl = rl[0][cl] + rl[1][cl] + rl[2][cl] + rl[3][cl];
        out[b * CD + cq * 64 + cl] = sn / sl;
    }
}

extern "C" void kernel_launch(void* const* d_in, const int* in_sizes, int n_in,
                              void* d_out, int out_size, void* d_ws, size_t ws_size,
                              hipStream_t stream)
{
    (void)in_sizes; (void)n_in; (void)out_size; (void)ws_size;
    const float* V      = (const float*)d_in[0];
    const float* h_t    = (const float*)d_in[1];
    const float* W_h_w  = (const float*)d_in[2];
    const float* W_h_b  = (const float*)d_in[3];
    const float* W_w    = (const float*)d_in[4];
    const float* W_b    = (const float*)d_in[5];
    const float* beta_w = (const float*)d_in[6];
    const float* beta_b = (const float*)d_in[7];

    char* ws = (char*)d_ws;
    ush*   wwb = (ush*)ws;                                   // 256 KB
    ush*   hws = (ush*)(ws + 262144);                        // 64 KB
    float* num = (float*)(ws + 262144 + 65536);              // 8.4 MB
    float* lsm = (float*)(ws + 262144 + 65536 + 8388608);    // 32 KB

    hipLaunchKernelGGL(prep_kernel, dim3(96), dim3(512), 0, stream,
                       h_t, W_h_w, W_h_b, W_w, W_b, hws, wwb);
    hipLaunchKernelGGL(fused, dim3(256), dim3(1024), 0, stream,
                       V, wwb, hws, beta_w, beta_b, num, lsm);
    hipLaunchKernelGGL(combine4, dim3(256), dim3(256), 0, stream,
                       num, lsm, (float*)d_out);
}